// Round 5
// baseline (163.864 us; speedup 1.0000x reference)
//
#include <hip/hip_runtime.h>
#include <math.h>

#define BB 32
#define CC 384
#define HH 56
#define WW 56
#define HWSZ (HH*WW)          // 3136
#define EPSF 1e-6f

#define TQ 16                 // tile quads per row (64 floats)
#define TROWS 34              // 28 outputs + 6 halo
#define TILE_F (TROWS*TQ*4)   // 2176 floats = 8704 B per wave

typedef float floatx4 __attribute__((ext_vector_type(4)));

// ---------------- kernel 1: per-(b,c) mean + max over H*W ----------------
__global__ __launch_bounds__(256) void pool_kernel(const float* __restrict__ x,
                                                   float* __restrict__ xavg,
                                                   float* __restrict__ xmax) {
    int plane = blockIdx.x;                       // b*C + c
    const float4* xp = (const float4*)(x + (size_t)plane * HWSZ);
    int t = threadIdx.x;
    float s = 0.f, m = -INFINITY;
    for (int i = t; i < HWSZ/4; i += 256) {       // 784 float4
        float4 v = xp[i];
        s += v.x + v.y + v.z + v.w;
        m = fmaxf(m, fmaxf(fmaxf(v.x, v.y), fmaxf(v.z, v.w)));
    }
    for (int off = 32; off; off >>= 1) {
        s += __shfl_down(s, off, 64);
        m = fmaxf(m, __shfl_down(m, off, 64));
    }
    __shared__ float ss[4], sm[4];
    int wid = t >> 6;
    if ((t & 63) == 0) { ss[wid] = s; sm[wid] = m; }
    __syncthreads();
    if (t == 0) {
        s = ss[0] + ss[1] + ss[2] + ss[3];
        m = fmaxf(fmaxf(sm[0], sm[1]), fmaxf(sm[2], sm[3]));
        xavg[plane] = s * (1.0f / HWSZ);
        xmax[plane] = m;
    }
}

// ---------------- kernel 2: GEMVs + GELU + FGRN -> per-sample 7x7 kernels ----------------
__global__ __launch_bounds__(384) void weights_kernel(
        const float* __restrict__ xavg, const float* __restrict__ xmax,
        const float* __restrict__ w_avg, const float* __restrict__ b_avg,
        const float* __restrict__ w_max, const float* __restrict__ b_max,
        const float* __restrict__ w_mix, const float* __restrict__ gamma,
        const float* __restrict__ beta, float* __restrict__ kern) {
    int b = blockIdx.x, c = threadIdx.x;
    __shared__ float xa[CC], xm[CC], red[512];
    xa[c] = xavg[b*CC + c];
    xm[c] = xmax[b*CC + c];
    if (c < 512 - CC) red[CC + c] = 0.f;
    __syncthreads();

    const float4* wa = (const float4*)(w_avg + (size_t)c * CC);
    const float4* wm = (const float4*)(w_max + (size_t)c * CC);
    float acc = b_avg[c] + b_max[c];
    #pragma unroll 4
    for (int q = 0; q < CC/4; ++q) {
        float4 a4 = wa[q], m4 = wm[q];
        const float* xap = &xa[q*4];
        const float* xmp = &xm[q*4];
        acc += a4.x*xap[0] + a4.y*xap[1] + a4.z*xap[2] + a4.w*xap[3];
        acc += m4.x*xmp[0] + m4.y*xmp[1] + m4.z*xmp[2] + m4.w*xmp[3];
    }
    float xw = 0.5f * acc * (1.0f + erff(acc * 0.70710678118654752f));

    float wrow[49];
    float sq = 0.f;
    const float* wmx = w_mix + c*49;
    #pragma unroll
    for (int j = 0; j < 49; ++j) { wrow[j] = wmx[j]; sq += wrow[j]*wrow[j]; }
    float Gx = fabsf(xw) * sqrtf(sq);

    red[c] = Gx;
    __syncthreads();
    for (int off = 256; off > 0; off >>= 1) {
        if (c < off) red[c] += red[c + off];
        __syncthreads();
    }
    float meanG = red[0] * (1.0f / CC);
    float Nx = Gx / (meanG + EPSF);

    float g = gamma[c], bt = beta[c];
    float coef = g * xw * Nx;
    float* kp = kern + ((size_t)(b*CC + c)) * 49;
    #pragma unroll
    for (int j = 0; j < 49; ++j) kp[j] = coef * wrow[j] + bt;
}

// ---------------- kernel 3: dynamic depthwise 7x7 conv ----------------
// 128 threads = 2 waves; wave w computes half-tile w (28 output rows) of plane
// blockIdx.x. No block barriers. LDS 8704 B/wave -> 9 blocks/CU (18 waves/CU).
// Tile: 34 rows x 16 quads, XOR-swizzled: logical quad q of row r stored at
// physical quad q^(r&7). Lane (s,g): 4-wide x 7-tall patch.
__global__ __launch_bounds__(128, 4) void conv_kernel(const float* __restrict__ x,
                                                      const float* __restrict__ kern,
                                                      float* __restrict__ out) {
    int t = threadIdx.x;
    int wave = t >> 6;                   // 0,1 = which half
    int lane = t & 63;
    int plane = blockIdx.x;
    int h = wave;
    const float4* xp4 = (const float4*)(x + (size_t)plane * HWSZ);
    float4* op4 = (float4*)(out + (size_t)plane * HWSZ);

    __shared__ float lds[2 * TILE_F];    // 17408 B
    float* tile = &lds[wave * TILE_F];

    // ---- prefetch staging loads into registers (31 rows x 14 quads = 434 float4)
    int r_lo   = (h == 0) ? 0 : 25;
    int tr_off = (h == 0) ? 3 : 0;
    const float4* src = xp4 + r_lo * 14;
    float4 pf[7];
    #pragma unroll
    for (int i = 0; i < 7; ++i) {
        int idx = lane + 64*i;
        if (idx < 434) pf[i] = src[idx];
    }

    // ---- kernel taps -> wave-uniform SGPRs (overlaps load latency)
    float kfv[49];
    {
        const float* kp = kern + (size_t)plane * 49;
        #pragma unroll
        for (int j = 0; j < 49; ++j) {
            union { float f; int i; } u;
            u.f = kp[j];
            u.i = __builtin_amdgcn_readfirstlane(u.i);
            kfv[j] = u.f;
        }
    }

    float4 z4 = make_float4(0.f, 0.f, 0.f, 0.f);
    // ---- zero side quads (logical quads 0 and 15) for all 34 rows
    for (int i = lane; i < 68; i += 64) {
        int r = (i < 34) ? i : (i - 34);
        int q = (i < 34) ? 0 : 15;
        *(float4*)&tile[r*64 + ((q ^ (r & 7)) << 2)] = z4;
    }
    // ---- zero 3 full halo rows (h=0: rows 0..2; h=1: rows 31..33)
    if (lane < 48) {
        int r = ((h == 0) ? 0 : 31) + (lane >> 4);
        int q = lane & 15;
        *(float4*)&tile[r*64 + ((q ^ (r & 7)) << 2)] = z4;
    }
    // ---- write staged data: input (rr, qq) -> tile row rr+tr_off, logical quad qq+1
    #pragma unroll
    for (int i = 0; i < 7; ++i) {
        int idx = lane + 64*i;
        if (idx < 434) {
            int rr = idx / 14;
            int qq = idx - rr*14;
            int r  = rr + tr_off;
            *(float4*)&tile[r*64 + (((qq + 1) ^ (r & 7)) << 2)] = pf[i];
        }
    }
    asm volatile("s_waitcnt lgkmcnt(0)" ::: "memory");

    int s = lane & 15;
    int g = lane >> 4;                   // 0..3
    bool active = (s < 14);
    int sc = active ? s : 0;

    float acc[7][4];
    #pragma unroll
    for (int i = 0; i < 7; ++i)
        #pragma unroll
        for (int j = 0; j < 4; ++j) acc[i][j] = 0.f;

    // out(7g+oy, 4sc+j) += k[ky][kx] * input(7g+oy+ky-3, 4sc+j+kx-3)
    // tile row R = 7g+ry holds input row (28h + 7g + ry - 3); logical quads sc..sc+2
    // hold tile cols 4sc..4sc+11 = input cols 4sc-4..4sc+7.
    #pragma unroll
    for (int ry = 0; ry < 13; ++ry) {
        int R = 7*g + ry;
        int m = R & 7;
        const float* rowp = &tile[R*64];
        float rv[12];
        #pragma unroll
        for (int q = 0; q < 3; ++q)
            *(float4*)&rv[q*4] = *(const float4*)&rowp[((sc + q) ^ m) << 2];

        int oy_lo = (ry - 6 > 0) ? (ry - 6) : 0;
        int oy_hi = (ry < 6) ? ry : 6;
        #pragma unroll
        for (int oy = 0; oy < 7; ++oy) {
            if (oy < oy_lo || oy > oy_hi) continue;
            int ky = ry - oy;
            #pragma unroll
            for (int kx = 0; kx < 7; ++kx) {
                float kv = kfv[ky*7 + kx];
                #pragma unroll
                for (int j = 0; j < 4; ++j)
                    acc[oy][j] = fmaf(kv, rv[j + 1 + kx], acc[oy][j]);
            }
        }
    }

    if (active) {
        #pragma unroll
        for (int oy = 0; oy < 7; ++oy) {
            int orow = h*28 + 7*g + oy;
            floatx4 o;
            o.x = acc[oy][0]; o.y = acc[oy][1]; o.z = acc[oy][2]; o.w = acc[oy][3];
            __builtin_nontemporal_store(o, (floatx4*)&op4[orow*14 + sc]);
        }
    }
}

extern "C" void kernel_launch(void* const* d_in, const int* in_sizes, int n_in,
                              void* d_out, int out_size, void* d_ws, size_t ws_size,
                              hipStream_t stream) {
    const float* x     = (const float*)d_in[0];
    const float* w_avg = (const float*)d_in[1];
    const float* b_avg = (const float*)d_in[2];
    const float* w_max = (const float*)d_in[3];
    const float* b_max = (const float*)d_in[4];
    const float* w_mix = (const float*)d_in[5];
    const float* gamma = (const float*)d_in[6];
    const float* beta  = (const float*)d_in[7];
    float* out = (float*)d_out;

    float* ws   = (float*)d_ws;
    float* xavg = ws;                       // B*C
    float* xmax = ws + BB*CC;               // B*C
    float* kern = ws + 2*BB*CC;             // B*C*49

    pool_kernel<<<BB*CC, 256, 0, stream>>>(x, xavg, xmax);
    weights_kernel<<<BB, CC, 0, stream>>>(xavg, xmax, w_avg, b_avg, w_max, b_max,
                                          w_mix, gamma, beta, kern);
    conv_kernel<<<BB*CC, 128, 0, stream>>>(x, kern, out);
}

// Round 6
// 141.089 us; speedup vs baseline: 1.1614x; 1.1614x over previous
//
#include <hip/hip_runtime.h>
#include <math.h>

#define BB 32
#define CC 384
#define HH 56
#define WW 56
#define HWSZ (HH*WW)          // 3136
#define EPSF 1e-6f

#define TQ 16                 // tile quads per row (64 floats)
#define TROWS 34              // 28 outputs + 6 halo
#define TILE_F (TROWS*TQ*4)   // 2176 floats = 8704 B per wave

// ---------------- kernel 1: per-(b,c) mean + max over H*W ----------------
__global__ __launch_bounds__(256) void pool_kernel(const float* __restrict__ x,
                                                   float* __restrict__ xavg,
                                                   float* __restrict__ xmax) {
    int plane = blockIdx.x;                       // b*C + c
    const float4* xp = (const float4*)(x + (size_t)plane * HWSZ);
    int t = threadIdx.x;
    float s = 0.f, m = -INFINITY;
    for (int i = t; i < HWSZ/4; i += 256) {       // 784 float4
        float4 v = xp[i];
        s += v.x + v.y + v.z + v.w;
        m = fmaxf(m, fmaxf(fmaxf(v.x, v.y), fmaxf(v.z, v.w)));
    }
    for (int off = 32; off; off >>= 1) {
        s += __shfl_down(s, off, 64);
        m = fmaxf(m, __shfl_down(m, off, 64));
    }
    __shared__ float ss[4], sm[4];
    int wid = t >> 6;
    if ((t & 63) == 0) { ss[wid] = s; sm[wid] = m; }
    __syncthreads();
    if (t == 0) {
        s = ss[0] + ss[1] + ss[2] + ss[3];
        m = fmaxf(fmaxf(sm[0], sm[1]), fmaxf(sm[2], sm[3]));
        xavg[plane] = s * (1.0f / HWSZ);
        xmax[plane] = m;
    }
}

// ---------------- kernel 2: GEMVs + GELU + Gx (parallel) ----------------
// grid = 32 b x 6 channel-chunks = 192 blocks, 256 threads.
// 4 lanes per output channel split the K=384 dot; shuffle-reduce.
// Writes xw[b,c], Gx[b,c], and per-block partial sum partG[block] (deterministic).
__global__ __launch_bounds__(256) void gemv_kernel(
        const float* __restrict__ xavg, const float* __restrict__ xmax,
        const float* __restrict__ w_avg, const float* __restrict__ b_avg,
        const float* __restrict__ w_max, const float* __restrict__ b_max,
        const float* __restrict__ w_mix,
        float* __restrict__ xw, float* __restrict__ Gx, float* __restrict__ partG) {
    int blk = blockIdx.x;
    int b  = blk / 6;
    int cg = blk - b*6;
    int t  = threadIdx.x;
    int ch = cg*64 + (t >> 2);           // output channel
    int kl = t & 3;                      // k-split lane

    const float4* wa = (const float4*)(w_avg + (size_t)ch * CC) + kl*24;
    const float4* wm = (const float4*)(w_max + (size_t)ch * CC) + kl*24;
    const float4* xa = (const float4*)(xavg + (size_t)b * CC) + kl*24;
    const float4* xm = (const float4*)(xmax + (size_t)b * CC) + kl*24;

    float acc = 0.f;
    #pragma unroll 4
    for (int q = 0; q < 24; ++q) {
        float4 a4 = wa[q], v4 = xa[q];
        acc += a4.x*v4.x + a4.y*v4.y + a4.z*v4.z + a4.w*v4.w;
    }
    #pragma unroll 4
    for (int q = 0; q < 24; ++q) {
        float4 m4 = wm[q], v4 = xm[q];
        acc += m4.x*v4.x + m4.y*v4.y + m4.z*v4.z + m4.w*v4.w;
    }
    acc += __shfl_xor(acc, 1);
    acc += __shfl_xor(acc, 2);

    float val = acc + b_avg[ch] + b_max[ch];
    float xwv = 0.5f * val * (1.0f + erff(val * 0.70710678118654752f));

    // ||w_mix[ch,:]||^2, split over 4 lanes
    float sq = 0.f;
    const float* wr = w_mix + (size_t)ch * 49;
    #pragma unroll
    for (int i = 0; i < 13; ++i) {
        int j = kl + 4*i;
        if (j < 49) { float v = wr[j]; sq += v*v; }
    }
    sq += __shfl_xor(sq, 1);
    sq += __shfl_xor(sq, 2);
    float Gxv = fabsf(xwv) * sqrtf(sq);

    __shared__ float sg[64];
    if (kl == 0) {
        xw[b*CC + ch] = xwv;
        Gx[b*CC + ch] = Gxv;
        sg[t >> 2] = Gxv;
    }
    __syncthreads();
    if (t < 64) {
        float v = sg[t];
        for (int off = 32; off; off >>= 1) v += __shfl_down(v, off, 64);
        if (t == 0) partG[blk] = v;
    }
}

// ---------------- kernel 3: tap synthesis + dynamic depthwise 7x7 conv ----------------
// 128 threads = 2 waves; wave w computes half-tile w (28 output rows) of plane
// blockIdx.x. No block barriers. LDS 8704 B/wave.
// Tile: 34 rows x 16 quads, XOR-swizzled: logical quad q of row r at physical q^(r&7).
__global__ __launch_bounds__(128, 4) void conv_kernel(const float* __restrict__ x,
                                                      const float* __restrict__ xw,
                                                      const float* __restrict__ Gx,
                                                      const float* __restrict__ partG,
                                                      const float* __restrict__ w_mix,
                                                      const float* __restrict__ gamma,
                                                      const float* __restrict__ beta,
                                                      float* __restrict__ out) {
    int t = threadIdx.x;
    int wave = t >> 6;                   // 0,1 = which half
    int lane = t & 63;
    int plane = blockIdx.x;
    int h = wave;
    const float4* xp4 = (const float4*)(x + (size_t)plane * HWSZ);
    float4* op4 = (float4*)(out + (size_t)plane * HWSZ);

    __shared__ float lds[2 * TILE_F];    // 17408 B
    float* tile = &lds[wave * TILE_F];

    // ---- prefetch staging loads into registers (31 rows x 14 quads = 434 float4)
    int r_lo   = (h == 0) ? 0 : 25;
    int tr_off = (h == 0) ? 3 : 0;
    const float4* src = xp4 + r_lo * 14;
    float4 pf[7];
    #pragma unroll
    for (int i = 0; i < 7; ++i) {
        int idx = lane + 64*i;
        if (idx < 434) pf[i] = src[idx];
    }

    // ---- tap synthesis: kfv[j] = gamma[c]*xw*Nx * w_mix[c,j] + beta[c]  (wave-uniform SGPRs)
    float kfv[49];
    {
        int b = plane / CC;
        int c = plane - b*CC;
        float sG = partG[b*6+0] + partG[b*6+1] + partG[b*6+2]
                 + partG[b*6+3] + partG[b*6+4] + partG[b*6+5];
        float xwv = xw[plane];
        float Gxv = Gx[plane];
        float gam = gamma[c];
        float bet = beta[c];
        float coef = gam * xwv * (Gxv / (sG * (1.0f/CC) + EPSF));
        const float* wr = w_mix + (size_t)c * 49;
        #pragma unroll
        for (int j = 0; j < 49; ++j) {
            union { float f; int i; } u;
            u.f = coef * wr[j] + bet;
            u.i = __builtin_amdgcn_readfirstlane(u.i);
            kfv[j] = u.f;
        }
    }

    float4 z4 = make_float4(0.f, 0.f, 0.f, 0.f);
    // ---- zero side quads (logical quads 0 and 15) for all 34 rows
    for (int i = lane; i < 68; i += 64) {
        int r = (i < 34) ? i : (i - 34);
        int q = (i < 34) ? 0 : 15;
        *(float4*)&tile[r*64 + ((q ^ (r & 7)) << 2)] = z4;
    }
    // ---- zero 3 full halo rows (h=0: rows 0..2; h=1: rows 31..33)
    if (lane < 48) {
        int r = ((h == 0) ? 0 : 31) + (lane >> 4);
        int q = lane & 15;
        *(float4*)&tile[r*64 + ((q ^ (r & 7)) << 2)] = z4;
    }
    // ---- write staged data: input (rr, qq) -> tile row rr+tr_off, logical quad qq+1
    #pragma unroll
    for (int i = 0; i < 7; ++i) {
        int idx = lane + 64*i;
        if (idx < 434) {
            int rr = idx / 14;
            int qq = idx - rr*14;
            int r  = rr + tr_off;
            *(float4*)&tile[r*64 + (((qq + 1) ^ (r & 7)) << 2)] = pf[i];
        }
    }
    asm volatile("s_waitcnt lgkmcnt(0)" ::: "memory");

    int s = lane & 15;
    int g = lane >> 4;                   // 0..3
    bool active = (s < 14);
    int sc = active ? s : 0;

    float acc[7][4];
    #pragma unroll
    for (int i = 0; i < 7; ++i)
        #pragma unroll
        for (int j = 0; j < 4; ++j) acc[i][j] = 0.f;

    // out(7g+oy, 4sc+j) += k[ky][kx] * input(7g+oy+ky-3, 4sc+j+kx-3)
    #pragma unroll
    for (int ry = 0; ry < 13; ++ry) {
        int R = 7*g + ry;
        int m = R & 7;
        const float* rowp = &tile[R*64];
        float rv[12];
        #pragma unroll
        for (int q = 0; q < 3; ++q)
            *(float4*)&rv[q*4] = *(const float4*)&rowp[((sc + q) ^ m) << 2];

        int oy_lo = (ry - 6 > 0) ? (ry - 6) : 0;
        int oy_hi = (ry < 6) ? ry : 6;
        #pragma unroll
        for (int oy = 0; oy < 7; ++oy) {
            if (oy < oy_lo || oy > oy_hi) continue;
            int ky = ry - oy;
            #pragma unroll
            for (int kx = 0; kx < 7; ++kx) {
                float kv = kfv[ky*7 + kx];
                #pragma unroll
                for (int j = 0; j < 4; ++j)
                    acc[oy][j] = fmaf(kv, rv[j + 1 + kx], acc[oy][j]);
            }
        }
    }

    if (active) {
        #pragma unroll
        for (int oy = 0; oy < 7; ++oy) {
            int orow = h*28 + 7*g + oy;
            float4 o; o.x = acc[oy][0]; o.y = acc[oy][1]; o.z = acc[oy][2]; o.w = acc[oy][3];
            op4[orow*14 + sc] = o;
        }
    }
}

extern "C" void kernel_launch(void* const* d_in, const int* in_sizes, int n_in,
                              void* d_out, int out_size, void* d_ws, size_t ws_size,
                              hipStream_t stream) {
    const float* x     = (const float*)d_in[0];
    const float* w_avg = (const float*)d_in[1];
    const float* b_avg = (const float*)d_in[2];
    const float* w_max = (const float*)d_in[3];
    const float* b_max = (const float*)d_in[4];
    const float* w_mix = (const float*)d_in[5];
    const float* gamma = (const float*)d_in[6];
    const float* beta  = (const float*)d_in[7];
    float* out = (float*)d_out;

    float* ws    = (float*)d_ws;
    float* xavg  = ws;                      // B*C
    float* xmax  = ws + BB*CC;              // B*C
    float* xwbuf = ws + 2*BB*CC;            // B*C
    float* Gxbuf = ws + 3*BB*CC;            // B*C
    float* partG = ws + 4*BB*CC;            // 192

    pool_kernel<<<BB*CC, 256, 0, stream>>>(x, xavg, xmax);
    gemv_kernel<<<BB*6, 256, 0, stream>>>(xavg, xmax, w_avg, b_avg, w_max, b_max,
                                          w_mix, xwbuf, Gxbuf, partG);
    conv_kernel<<<BB*CC, 128, 0, stream>>>(x, xwbuf, Gxbuf, partG, w_mix, gamma, beta, out);
}

// Round 7
// 133.946 us; speedup vs baseline: 1.2234x; 1.0533x over previous
//
#include <hip/hip_runtime.h>
#include <math.h>

#define BB 32
#define CC 384
#define HH 56
#define WW 56
#define HWSZ (HH*WW)          // 3136
#define EPSF 1e-6f

#define TQ 16                 // tile quads per row (64 floats)
#define TROWS 34              // 28 outputs + 6 halo
#define TILE_F (TROWS*TQ*4)   // 2176 floats = 8704 B per wave

// ---------------- kernel 1: per-(b,c) mean + max over H*W ----------------
__global__ __launch_bounds__(256) void pool_kernel(const float* __restrict__ x,
                                                   float* __restrict__ xavg,
                                                   float* __restrict__ xmax) {
    int plane = blockIdx.x;                       // b*C + c
    const float4* xp = (const float4*)(x + (size_t)plane * HWSZ);
    int t = threadIdx.x;
    float s = 0.f, m = -INFINITY;
    for (int i = t; i < HWSZ/4; i += 256) {       // 784 float4
        float4 v = xp[i];
        s += v.x + v.y + v.z + v.w;
        m = fmaxf(m, fmaxf(fmaxf(v.x, v.y), fmaxf(v.z, v.w)));
    }
    for (int off = 32; off; off >>= 1) {
        s += __shfl_down(s, off, 64);
        m = fmaxf(m, __shfl_down(m, off, 64));
    }
    __shared__ float ss[4], sm[4];
    int wid = t >> 6;
    if ((t & 63) == 0) { ss[wid] = s; sm[wid] = m; }
    __syncthreads();
    if (t == 0) {
        s = ss[0] + ss[1] + ss[2] + ss[3];
        m = fmaxf(fmaxf(sm[0], sm[1]), fmaxf(sm[2], sm[3]));
        xavg[plane] = s * (1.0f / HWSZ);
        xmax[plane] = m;
    }
}

// ---------------- kernel 2: GEMVs + GELU + Gx (parallel) ----------------
// grid = 32 b x 6 channel-chunks = 192 blocks, 256 threads.
// 4 lanes per output channel split the K=384 dot; shuffle-reduce.
// Writes xw[b,c], Gx[b,c], and per-block partial sum partG[block] (deterministic).
__global__ __launch_bounds__(256) void gemv_kernel(
        const float* __restrict__ xavg, const float* __restrict__ xmax,
        const float* __restrict__ w_avg, const float* __restrict__ b_avg,
        const float* __restrict__ w_max, const float* __restrict__ b_max,
        const float* __restrict__ w_mix,
        float* __restrict__ xw, float* __restrict__ Gx, float* __restrict__ partG) {
    int blk = blockIdx.x;
    int b  = blk / 6;
    int cg = blk - b*6;
    int t  = threadIdx.x;
    int ch = cg*64 + (t >> 2);           // output channel
    int kl = t & 3;                      // k-split lane

    const float4* wa = (const float4*)(w_avg + (size_t)ch * CC) + kl*24;
    const float4* wm = (const float4*)(w_max + (size_t)ch * CC) + kl*24;
    const float4* xa = (const float4*)(xavg + (size_t)b * CC) + kl*24;
    const float4* xm = (const float4*)(xmax + (size_t)b * CC) + kl*24;

    float acc = 0.f;
    #pragma unroll 4
    for (int q = 0; q < 24; ++q) {
        float4 a4 = wa[q], v4 = xa[q];
        acc += a4.x*v4.x + a4.y*v4.y + a4.z*v4.z + a4.w*v4.w;
    }
    #pragma unroll 4
    for (int q = 0; q < 24; ++q) {
        float4 m4 = wm[q], v4 = xm[q];
        acc += m4.x*v4.x + m4.y*v4.y + m4.z*v4.z + m4.w*v4.w;
    }
    acc += __shfl_xor(acc, 1);
    acc += __shfl_xor(acc, 2);

    float val = acc + b_avg[ch] + b_max[ch];
    float xwv = 0.5f * val * (1.0f + erff(val * 0.70710678118654752f));

    // ||w_mix[ch,:]||^2, split over 4 lanes
    float sq = 0.f;
    const float* wr = w_mix + (size_t)ch * 49;
    #pragma unroll
    for (int i = 0; i < 13; ++i) {
        int j = kl + 4*i;
        if (j < 49) { float v = wr[j]; sq += v*v; }
    }
    sq += __shfl_xor(sq, 1);
    sq += __shfl_xor(sq, 2);
    float Gxv = fabsf(xwv) * sqrtf(sq);

    __shared__ float sg[64];
    if (kl == 0) {
        xw[b*CC + ch] = xwv;
        Gx[b*CC + ch] = Gxv;
        sg[t >> 2] = Gxv;
    }
    __syncthreads();
    if (t < 64) {
        float v = sg[t];
        for (int off = 32; off; off >>= 1) v += __shfl_down(v, off, 64);
        if (t == 0) partG[blk] = v;
    }
}

// ---------------- kernel 3: tap synthesis + dynamic depthwise 7x7 conv ----------------
// 128 threads = 2 waves; wave w computes half-tile w (28 output rows) of plane
// blockIdx.x. No block barriers. LDS 8704 B/wave.
// Tile: 34 rows x 16 quads, XOR-swizzled: logical quad q of row r at physical q^(r&7).
// launch_bounds (128,2): give regalloc headroom (the (128,4) build spilled at
// VGPR=64 -> +174MB scratch traffic to HBM).
__global__ __launch_bounds__(128, 2) void conv_kernel(const float* __restrict__ x,
                                                      const float* __restrict__ xw,
                                                      const float* __restrict__ Gx,
                                                      const float* __restrict__ partG,
                                                      const float* __restrict__ w_mix,
                                                      const float* __restrict__ gamma,
                                                      const float* __restrict__ beta,
                                                      float* __restrict__ out) {
    int t = threadIdx.x;
    int wave = t >> 6;                   // 0,1 = which half
    int lane = t & 63;
    int plane = blockIdx.x;
    int h = wave;
    const float4* xp4 = (const float4*)(x + (size_t)plane * HWSZ);
    float4* op4 = (float4*)(out + (size_t)plane * HWSZ);

    __shared__ float lds[2 * TILE_F];    // 17408 B
    float* tile = &lds[wave * TILE_F];

    // ---- prefetch staging loads into registers (31 rows x 14 quads = 434 float4)
    int r_lo   = (h == 0) ? 0 : 25;
    int tr_off = (h == 0) ? 3 : 0;
    const float4* src = xp4 + r_lo * 14;
    float4 pf[7];
    #pragma unroll
    for (int i = 0; i < 7; ++i) {
        int idx = lane + 64*i;
        if (idx < 434) pf[i] = src[idx];
    }

    // ---- tap synthesis: kfv[j] = gamma[c]*xw*Nx * w_mix[c,j] + beta[c]  (wave-uniform SGPRs)
    float kfv[49];
    {
        int b = plane / CC;
        int c = plane - b*CC;
        float sG = partG[b*6+0] + partG[b*6+1] + partG[b*6+2]
                 + partG[b*6+3] + partG[b*6+4] + partG[b*6+5];
        float xwv = xw[plane];
        float Gxv = Gx[plane];
        float gam = gamma[c];
        float bet = beta[c];
        float coef = gam * xwv * (Gxv / (sG * (1.0f/CC) + EPSF));
        const float* wr = w_mix + (size_t)c * 49;
        #pragma unroll
        for (int j = 0; j < 49; ++j) {
            union { float f; int i; } u;
            u.f = coef * wr[j] + bet;
            u.i = __builtin_amdgcn_readfirstlane(u.i);
            kfv[j] = u.f;
        }
    }

    float4 z4 = make_float4(0.f, 0.f, 0.f, 0.f);
    // ---- zero side quads (logical quads 0 and 15) for all 34 rows
    for (int i = lane; i < 68; i += 64) {
        int r = (i < 34) ? i : (i - 34);
        int q = (i < 34) ? 0 : 15;
        *(float4*)&tile[r*64 + ((q ^ (r & 7)) << 2)] = z4;
    }
    // ---- zero 3 full halo rows (h=0: rows 0..2; h=1: rows 31..33)
    if (lane < 48) {
        int r = ((h == 0) ? 0 : 31) + (lane >> 4);
        int q = lane & 15;
        *(float4*)&tile[r*64 + ((q ^ (r & 7)) << 2)] = z4;
    }
    // ---- write staged data: input (rr, qq) -> tile row rr+tr_off, logical quad qq+1
    #pragma unroll
    for (int i = 0; i < 7; ++i) {
        int idx = lane + 64*i;
        if (idx < 434) {
            int rr = idx / 14;
            int qq = idx - rr*14;
            int r  = rr + tr_off;
            *(float4*)&tile[r*64 + (((qq + 1) ^ (r & 7)) << 2)] = pf[i];
        }
    }
    asm volatile("s_waitcnt lgkmcnt(0)" ::: "memory");

    int s = lane & 15;
    int g = lane >> 4;                   // 0..3
    bool active = (s < 14);
    int sc = active ? s : 0;

    float acc[7][4];
    #pragma unroll
    for (int i = 0; i < 7; ++i)
        #pragma unroll
        for (int j = 0; j < 4; ++j) acc[i][j] = 0.f;

    // out(7g+oy, 4sc+j) += k[ky][kx] * input(7g+oy+ky-3, 4sc+j+kx-3)
    #pragma unroll
    for (int ry = 0; ry < 13; ++ry) {
        int R = 7*g + ry;
        int m = R & 7;
        const float* rowp = &tile[R*64];
        float rv[12];
        #pragma unroll
        for (int q = 0; q < 3; ++q)
            *(float4*)&rv[q*4] = *(const float4*)&rowp[((sc + q) ^ m) << 2];

        int oy_lo = (ry - 6 > 0) ? (ry - 6) : 0;
        int oy_hi = (ry < 6) ? ry : 6;
        #pragma unroll
        for (int oy = 0; oy < 7; ++oy) {
            if (oy < oy_lo || oy > oy_hi) continue;
            int ky = ry - oy;
            #pragma unroll
            for (int kx = 0; kx < 7; ++kx) {
                float kv = kfv[ky*7 + kx];
                #pragma unroll
                for (int j = 0; j < 4; ++j)
                    acc[oy][j] = fmaf(kv, rv[j + 1 + kx], acc[oy][j]);
            }
        }
    }

    if (active) {
        #pragma unroll
        for (int oy = 0; oy < 7; ++oy) {
            int orow = h*28 + 7*g + oy;
            float4 o; o.x = acc[oy][0]; o.y = acc[oy][1]; o.z = acc[oy][2]; o.w = acc[oy][3];
            op4[orow*14 + sc] = o;
        }
    }
}

extern "C" void kernel_launch(void* const* d_in, const int* in_sizes, int n_in,
                              void* d_out, int out_size, void* d_ws, size_t ws_size,
                              hipStream_t stream) {
    const float* x     = (const float*)d_in[0];
    const float* w_avg = (const float*)d_in[1];
    const float* b_avg = (const float*)d_in[2];
    const float* w_max = (const float*)d_in[3];
    const float* b_max = (const float*)d_in[4];
    const float* w_mix = (const float*)d_in[5];
    const float* gamma = (const float*)d_in[6];
    const float* beta  = (const float*)d_in[7];
    float* out = (float*)d_out;

    float* ws    = (float*)d_ws;
    float* xavg  = ws;                      // B*C
    float* xmax  = ws + BB*CC;              // B*C
    float* xwbuf = ws + 2*BB*CC;            // B*C
    float* Gxbuf = ws + 3*BB*CC;            // B*C
    float* partG = ws + 4*BB*CC;            // 192

    pool_kernel<<<BB*CC, 256, 0, stream>>>(x, xavg, xmax);
    gemv_kernel<<<BB*6, 256, 0, stream>>>(xavg, xmax, w_avg, b_avg, w_max, b_max,
                                          w_mix, xwbuf, Gxbuf, partG);
    conv_kernel<<<BB*CC, 128, 0, stream>>>(x, xwbuf, Gxbuf, partG, w_mix, gamma, beta, out);
}

// Round 8
// 122.601 us; speedup vs baseline: 1.3366x; 1.0925x over previous
//
#include <hip/hip_runtime.h>
#include <math.h>

#define BB 32
#define CC 384
#define HH 56
#define WW 56
#define HWSZ (HH*WW)          // 3136
#define EPSF 1e-6f

// ---------------- kernel 1: per-(b,c) mean + max over H*W ----------------
__global__ __launch_bounds__(256) void pool_kernel(const float* __restrict__ x,
                                                   float* __restrict__ xavg,
                                                   float* __restrict__ xmax) {
    int plane = blockIdx.x;                       // b*C + c
    const float4* xp = (const float4*)(x + (size_t)plane * HWSZ);
    int t = threadIdx.x;
    float s = 0.f, m = -INFINITY;
    for (int i = t; i < HWSZ/4; i += 256) {       // 784 float4
        float4 v = xp[i];
        s += v.x + v.y + v.z + v.w;
        m = fmaxf(m, fmaxf(fmaxf(v.x, v.y), fmaxf(v.z, v.w)));
    }
    for (int off = 32; off; off >>= 1) {
        s += __shfl_down(s, off, 64);
        m = fmaxf(m, __shfl_down(m, off, 64));
    }
    __shared__ float ss[4], sm[4];
    int wid = t >> 6;
    if ((t & 63) == 0) { ss[wid] = s; sm[wid] = m; }
    __syncthreads();
    if (t == 0) {
        s = ss[0] + ss[1] + ss[2] + ss[3];
        m = fmaxf(fmaxf(sm[0], sm[1]), fmaxf(sm[2], sm[3]));
        xavg[plane] = s * (1.0f / HWSZ);
        xmax[plane] = m;
    }
}

// ---------------- kernel 2: GEMVs + GELU + Gx (parallel) ----------------
__global__ __launch_bounds__(256) void gemv_kernel(
        const float* __restrict__ xavg, const float* __restrict__ xmax,
        const float* __restrict__ w_avg, const float* __restrict__ b_avg,
        const float* __restrict__ w_max, const float* __restrict__ b_max,
        const float* __restrict__ w_mix,
        float* __restrict__ xw, float* __restrict__ Gx, float* __restrict__ partG) {
    int blk = blockIdx.x;
    int b  = blk / 6;
    int cg = blk - b*6;
    int t  = threadIdx.x;
    int ch = cg*64 + (t >> 2);           // output channel
    int kl = t & 3;                      // k-split lane

    const float4* wa = (const float4*)(w_avg + (size_t)ch * CC) + kl*24;
    const float4* wm = (const float4*)(w_max + (size_t)ch * CC) + kl*24;
    const float4* xa = (const float4*)(xavg + (size_t)b * CC) + kl*24;
    const float4* xm = (const float4*)(xmax + (size_t)b * CC) + kl*24;

    float acc = 0.f;
    #pragma unroll 4
    for (int q = 0; q < 24; ++q) {
        float4 a4 = wa[q], v4 = xa[q];
        acc += a4.x*v4.x + a4.y*v4.y + a4.z*v4.z + a4.w*v4.w;
    }
    #pragma unroll 4
    for (int q = 0; q < 24; ++q) {
        float4 m4 = wm[q], v4 = xm[q];
        acc += m4.x*v4.x + m4.y*v4.y + m4.z*v4.z + m4.w*v4.w;
    }
    acc += __shfl_xor(acc, 1);
    acc += __shfl_xor(acc, 2);

    float val = acc + b_avg[ch] + b_max[ch];
    float xwv = 0.5f * val * (1.0f + erff(val * 0.70710678118654752f));

    float sq = 0.f;
    const float* wr = w_mix + (size_t)ch * 49;
    #pragma unroll
    for (int i = 0; i < 13; ++i) {
        int j = kl + 4*i;
        if (j < 49) { float v = wr[j]; sq += v*v; }
    }
    sq += __shfl_xor(sq, 1);
    sq += __shfl_xor(sq, 2);
    float Gxv = fabsf(xwv) * sqrtf(sq);

    __shared__ float sg[64];
    if (kl == 0) {
        xw[b*CC + ch] = xwv;
        Gx[b*CC + ch] = Gxv;
        sg[t >> 2] = Gxv;
    }
    __syncthreads();
    if (t < 64) {
        float v = sg[t];
        for (int off = 32; off; off >>= 1) v += __shfl_down(v, off, 64);
        if (t == 0) partG[blk] = v;
    }
}

// ---------------- kernel 3: tap synthesis + direct-global depthwise 7x7 conv ----------------
// 128 threads = one plane. NO LDS. Lane (s,g): 4-wide x 7-tall output patch,
// rows [7g,7g+7), cols [4s,4s+4). 13 input rows x 3 float4 window per lane,
// served by L1/L2 (5.6x reuse). Boundary zeros via cndmask.
__global__ __launch_bounds__(128) void conv_kernel(const float* __restrict__ x,
                                                   const float* __restrict__ xw,
                                                   const float* __restrict__ Gx,
                                                   const float* __restrict__ partG,
                                                   const float* __restrict__ w_mix,
                                                   const float* __restrict__ gamma,
                                                   const float* __restrict__ beta,
                                                   float* __restrict__ out) {
    int t = threadIdx.x;
    int plane = blockIdx.x;
    const float4* xp4 = (const float4*)(x + (size_t)plane * HWSZ);
    float4* op4 = (float4*)(out + (size_t)plane * HWSZ);

    // ---- tap synthesis: kfv[j] = gamma[c]*xw*Nx * w_mix[c,j] + beta[c]  (wave-uniform SGPRs)
    float kfv[49];
    {
        int b = plane / CC;
        int c = plane - b*CC;
        float sG = partG[b*6+0] + partG[b*6+1] + partG[b*6+2]
                 + partG[b*6+3] + partG[b*6+4] + partG[b*6+5];
        float xwv = xw[plane];
        float Gxv = Gx[plane];
        float gam = gamma[c];
        float bet = beta[c];
        float coef = gam * xwv * (Gxv / (sG * (1.0f/CC) + EPSF));
        const float* wr = w_mix + (size_t)c * 49;
        #pragma unroll
        for (int j = 0; j < 49; ++j) {
            union { float f; int i; } u;
            u.f = coef * wr[j] + bet;
            u.i = __builtin_amdgcn_readfirstlane(u.i);
            kfv[j] = u.f;
        }
    }

    int s = t & 15;                      // 0..15 (14 active)
    int g = (t >> 4) & 7;                // 0..7 row-group
    bool active = (s < 14);
    int sc = active ? s : 13;

    float acc[7][4];
    #pragma unroll
    for (int i = 0; i < 7; ++i)
        #pragma unroll
        for (int j = 0; j < 4; ++j) acc[i][j] = 0.f;

    float4 z4 = make_float4(0.f, 0.f, 0.f, 0.f);

    // out(7g+oy, 4sc+j) += k[ky][kx] * in(7g+oy+ky-3, 4sc+j+kx-3)
    // rv[idx] = input col 4sc-4+idx; taps use idx = j+kx+1 in [1,10].
    #pragma unroll
    for (int ry = 0; ry < 13; ++ry) {
        int ri = 7*g + ry - 3;
        bool vr = ((unsigned)ri < 56u);
        int base = (vr ? ri : 0) * 14;
        float4 va = xp4[base + (sc > 0 ? sc - 1 : 0)];
        float4 vb = xp4[base + sc];
        float4 vc = xp4[base + (sc < 13 ? sc + 1 : 13)];
        if (!(vr && sc > 0))  va = z4;
        if (!vr)              vb = z4;
        if (!(vr && sc < 13)) vc = z4;
        float rv[12];
        rv[0]=va.x; rv[1]=va.y; rv[2]=va.z; rv[3]=va.w;
        rv[4]=vb.x; rv[5]=vb.y; rv[6]=vb.z; rv[7]=vb.w;
        rv[8]=vc.x; rv[9]=vc.y; rv[10]=vc.z; rv[11]=vc.w;

        int oy_lo = (ry - 6 > 0) ? (ry - 6) : 0;
        int oy_hi = (ry < 6) ? ry : 6;
        #pragma unroll
        for (int oy = 0; oy < 7; ++oy) {
            if (oy < oy_lo || oy > oy_hi) continue;
            int ky = ry - oy;
            #pragma unroll
            for (int kx = 0; kx < 7; ++kx) {
                float kv = kfv[ky*7 + kx];
                #pragma unroll
                for (int j = 0; j < 4; ++j)
                    acc[oy][j] = fmaf(kv, rv[j + 1 + kx], acc[oy][j]);
            }
        }
    }

    if (active) {
        #pragma unroll
        for (int oy = 0; oy < 7; ++oy) {
            int orow = 7*g + oy;
            float4 o; o.x = acc[oy][0]; o.y = acc[oy][1]; o.z = acc[oy][2]; o.w = acc[oy][3];
            op4[orow*14 + sc] = o;
        }
    }
}

extern "C" void kernel_launch(void* const* d_in, const int* in_sizes, int n_in,
                              void* d_out, int out_size, void* d_ws, size_t ws_size,
                              hipStream_t stream) {
    const float* x     = (const float*)d_in[0];
    const float* w_avg = (const float*)d_in[1];
    const float* b_avg = (const float*)d_in[2];
    const float* w_max = (const float*)d_in[3];
    const float* b_max = (const float*)d_in[4];
    const float* w_mix = (const float*)d_in[5];
    const float* gamma = (const float*)d_in[6];
    const float* beta  = (const float*)d_in[7];
    float* out = (float*)d_out;

    float* ws    = (float*)d_ws;
    float* xavg  = ws;                      // B*C
    float* xmax  = ws + BB*CC;              // B*C
    float* xwbuf = ws + 2*BB*CC;            // B*C
    float* Gxbuf = ws + 3*BB*CC;            // B*C
    float* partG = ws + 4*BB*CC;            // 192

    pool_kernel<<<BB*CC, 256, 0, stream>>>(x, xavg, xmax);
    gemv_kernel<<<BB*6, 256, 0, stream>>>(xavg, xmax, w_avg, b_avg, w_max, b_max,
                                          w_mix, xwbuf, Gxbuf, partG);
    conv_kernel<<<BB*CC, 128, 0, stream>>>(x, xwbuf, Gxbuf, partG, w_mix, gamma, beta, out);
}

// Round 9
// 102.853 us; speedup vs baseline: 1.5932x; 1.1920x over previous
//
#include <hip/hip_runtime.h>
#include <math.h>

#define BB 32
#define CC 384
#define HH 56
#define WW 56
#define HWSZ (HH*WW)          // 3136
#define EPSF 1e-6f

// DPP lane-shift within 16-lane rows, zero-fill at row edges (bound_ctrl).
__device__ __forceinline__ float dpp_shr1(float v) {   // lane s gets lane s-1's v; s==0 -> 0
    return __int_as_float(__builtin_amdgcn_update_dpp(
        0, __float_as_int(v), 0x111, 0xF, 0xF, true));
}
__device__ __forceinline__ float dpp_shl1(float v) {   // lane s gets lane s+1's v; s==15 -> 0
    return __int_as_float(__builtin_amdgcn_update_dpp(
        0, __float_as_int(v), 0x101, 0xF, 0xF, true));
}

// ---------------- kernel 1: per-(b,c) mean + max over H*W ----------------
__global__ __launch_bounds__(256) void pool_kernel(const float* __restrict__ x,
                                                   float* __restrict__ xavg,
                                                   float* __restrict__ xmax) {
    int plane = blockIdx.x;                       // b*C + c
    const float4* xp = (const float4*)(x + (size_t)plane * HWSZ);
    int t = threadIdx.x;
    float s = 0.f, m = -INFINITY;
    for (int i = t; i < HWSZ/4; i += 256) {       // 784 float4
        float4 v = xp[i];
        s += v.x + v.y + v.z + v.w;
        m = fmaxf(m, fmaxf(fmaxf(v.x, v.y), fmaxf(v.z, v.w)));
    }
    for (int off = 32; off; off >>= 1) {
        s += __shfl_down(s, off, 64);
        m = fmaxf(m, __shfl_down(m, off, 64));
    }
    __shared__ float ss[4], sm[4];
    int wid = t >> 6;
    if ((t & 63) == 0) { ss[wid] = s; sm[wid] = m; }
    __syncthreads();
    if (t == 0) {
        s = ss[0] + ss[1] + ss[2] + ss[3];
        m = fmaxf(fmaxf(sm[0], sm[1]), fmaxf(sm[2], sm[3]));
        xavg[plane] = s * (1.0f / HWSZ);
        xmax[plane] = m;
    }
}

// ---------------- kernel 2: GEMVs + GELU + Gx (parallel) ----------------
__global__ __launch_bounds__(256) void gemv_kernel(
        const float* __restrict__ xavg, const float* __restrict__ xmax,
        const float* __restrict__ w_avg, const float* __restrict__ b_avg,
        const float* __restrict__ w_max, const float* __restrict__ b_max,
        const float* __restrict__ w_mix,
        float* __restrict__ xw, float* __restrict__ Gx, float* __restrict__ partG) {
    int blk = blockIdx.x;
    int b  = blk / 6;
    int cg = blk - b*6;
    int t  = threadIdx.x;
    int ch = cg*64 + (t >> 2);           // output channel
    int kl = t & 3;                      // k-split lane

    const float4* wa = (const float4*)(w_avg + (size_t)ch * CC) + kl*24;
    const float4* wm = (const float4*)(w_max + (size_t)ch * CC) + kl*24;
    const float4* xa = (const float4*)(xavg + (size_t)b * CC) + kl*24;
    const float4* xm = (const float4*)(xmax + (size_t)b * CC) + kl*24;

    float acc = 0.f;
    #pragma unroll 4
    for (int q = 0; q < 24; ++q) {
        float4 a4 = wa[q], v4 = xa[q];
        acc += a4.x*v4.x + a4.y*v4.y + a4.z*v4.z + a4.w*v4.w;
    }
    #pragma unroll 4
    for (int q = 0; q < 24; ++q) {
        float4 m4 = wm[q], v4 = xm[q];
        acc += m4.x*v4.x + m4.y*v4.y + m4.z*v4.z + m4.w*v4.w;
    }
    acc += __shfl_xor(acc, 1);
    acc += __shfl_xor(acc, 2);

    float val = acc + b_avg[ch] + b_max[ch];
    float xwv = 0.5f * val * (1.0f + erff(val * 0.70710678118654752f));

    float sq = 0.f;
    const float* wr = w_mix + (size_t)ch * 49;
    #pragma unroll
    for (int i = 0; i < 13; ++i) {
        int j = kl + 4*i;
        if (j < 49) { float v = wr[j]; sq += v*v; }
    }
    sq += __shfl_xor(sq, 1);
    sq += __shfl_xor(sq, 2);
    float Gxv = fabsf(xwv) * sqrtf(sq);

    __shared__ float sg[64];
    if (kl == 0) {
        xw[b*CC + ch] = xwv;
        Gx[b*CC + ch] = Gxv;
        sg[t >> 2] = Gxv;
    }
    __syncthreads();
    if (t < 64) {
        float v = sg[t];
        for (int off = 32; off; off >>= 1) v += __shfl_down(v, off, 64);
        if (t == 0) partG[blk] = v;
    }
}

// ---------------- kernel 3: tap synthesis + direct-global depthwise 7x7 conv ----------------
// 128 threads = one plane, no LDS. Lane (s,g): 4-wide x 7-tall patch.
// One float4 load per tile row (13/lane); left/right neighbor floats via DPP
// row_shr/row_shl (16-lane rows == s dimension), bound_ctrl gives zero pad.
__global__ __launch_bounds__(128) void conv_kernel(const float* __restrict__ x,
                                                   const float* __restrict__ xw,
                                                   const float* __restrict__ Gx,
                                                   const float* __restrict__ partG,
                                                   const float* __restrict__ w_mix,
                                                   const float* __restrict__ gamma,
                                                   const float* __restrict__ beta,
                                                   float* __restrict__ out) {
    int t = threadIdx.x;
    int plane = blockIdx.x;
    const float4* xp4 = (const float4*)(x + (size_t)plane * HWSZ);
    float4* op4 = (float4*)(out + (size_t)plane * HWSZ);

    // ---- tap synthesis: kfv[j] = gamma[c]*xw*Nx * w_mix[c,j] + beta[c]  (wave-uniform SGPRs)
    float kfv[49];
    {
        int b = plane / CC;
        int c = plane - b*CC;
        float sG = partG[b*6+0] + partG[b*6+1] + partG[b*6+2]
                 + partG[b*6+3] + partG[b*6+4] + partG[b*6+5];
        float xwv = xw[plane];
        float Gxv = Gx[plane];
        float gam = gamma[c];
        float bet = beta[c];
        float coef = gam * xwv * (Gxv / (sG * (1.0f/CC) + EPSF));
        const float* wr = w_mix + (size_t)c * 49;
        #pragma unroll
        for (int j = 0; j < 49; ++j) {
            union { float f; int i; } u;
            u.f = coef * wr[j] + bet;
            u.i = __builtin_amdgcn_readfirstlane(u.i);
            kfv[j] = u.f;
        }
    }

    int s = t & 15;                      // col quad (14 active)
    int g = (t >> 4) & 7;                // row-group 0..7
    bool active = (s < 14);
    int sc = active ? s : 13;
    int g7 = 7*g - 3;                    // first input row of this group's window

    float acc[7][4];
    #pragma unroll
    for (int i = 0; i < 7; ++i)
        #pragma unroll
        for (int j = 0; j < 4; ++j) acc[i][j] = 0.f;

    float4 z4 = make_float4(0.f, 0.f, 0.f, 0.f);

    // out(7g+oy, 4s+j) += k[ky][kx] * in(7g+oy+ky-3, 4s+j+kx-3)
    // w[i] = input col 4s-3+i (i=0..9), from vb + DPP neighbors.
    #pragma unroll
    for (int ry = 0; ry < 13; ++ry) {
        int ri = g7 + ry;
        int ric = min(max(ri, 0), 55);
        float4 vb = xp4[ric*14 + sc];
        bool ok = ((unsigned)ri < 56u) && active;
        if (!ok) vb = z4;

        float w[10];
        w[0] = dpp_shr1(vb.y);           // col 4s-3 (lane s-1)
        w[1] = dpp_shr1(vb.z);
        w[2] = dpp_shr1(vb.w);
        w[3] = vb.x; w[4] = vb.y; w[5] = vb.z; w[6] = vb.w;
        w[7] = dpp_shl1(vb.x);           // col 4s+4 (lane s+1)
        w[8] = dpp_shl1(vb.y);
        w[9] = dpp_shl1(vb.z);

        int oy_lo = (ry - 6 > 0) ? (ry - 6) : 0;
        int oy_hi = (ry < 6) ? ry : 6;
        #pragma unroll
        for (int oy = 0; oy < 7; ++oy) {
            if (oy < oy_lo || oy > oy_hi) continue;
            int ky = ry - oy;
            #pragma unroll
            for (int kx = 0; kx < 7; ++kx) {
                float kv = kfv[ky*7 + kx];
                #pragma unroll
                for (int j = 0; j < 4; ++j)
                    acc[oy][j] = fmaf(kv, w[j + kx], acc[oy][j]);
            }
        }
    }

    if (active) {
        #pragma unroll
        for (int oy = 0; oy < 7; ++oy) {
            int orow = 7*g + oy;
            float4 o; o.x = acc[oy][0]; o.y = acc[oy][1]; o.z = acc[oy][2]; o.w = acc[oy][3];
            op4[orow*14 + sc] = o;
        }
    }
}

extern "C" void kernel_launch(void* const* d_in, const int* in_sizes, int n_in,
                              void* d_out, int out_size, void* d_ws, size_t ws_size,
                              hipStream_t stream) {
    const float* x     = (const float*)d_in[0];
    const float* w_avg = (const float*)d_in[1];
    const float* b_avg = (const float*)d_in[2];
    const float* w_max = (const float*)d_in[3];
    const float* b_max = (const float*)d_in[4];
    const float* w_mix = (const float*)d_in[5];
    const float* gamma = (const float*)d_in[6];
    const float* beta  = (const float*)d_in[7];
    float* out = (float*)d_out;

    float* ws    = (float*)d_ws;
    float* xavg  = ws;                      // B*C
    float* xmax  = ws + BB*CC;              // B*C
    float* xwbuf = ws + 2*BB*CC;            // B*C
    float* Gxbuf = ws + 3*BB*CC;            // B*C
    float* partG = ws + 4*BB*CC;            // 192

    pool_kernel<<<BB*CC, 256, 0, stream>>>(x, xavg, xmax);
    gemv_kernel<<<BB*6, 256, 0, stream>>>(xavg, xmax, w_avg, b_avg, w_max, b_max,
                                          w_mix, xwbuf, Gxbuf, partG);
    conv_kernel<<<BB*CC, 128, 0, stream>>>(x, xwbuf, Gxbuf, partG, w_mix, gamma, beta, out);
}

// Round 10
// 98.419 us; speedup vs baseline: 1.6650x; 1.0451x over previous
//
#include <hip/hip_runtime.h>
#include <math.h>

#define BB 32
#define CC 384
#define HH 56
#define WW 56
#define HWSZ (HH*WW)          // 3136
#define EPSF 1e-6f

typedef float float2v __attribute__((ext_vector_type(2)));

// DPP lane-shift within 16-lane rows, zero-fill at row edges (bound_ctrl).
__device__ __forceinline__ float dpp_shr1(float v) {   // lane s gets lane s-1's v; s==0 -> 0
    return __int_as_float(__builtin_amdgcn_update_dpp(
        0, __float_as_int(v), 0x111, 0xF, 0xF, true));
}
__device__ __forceinline__ float dpp_shl1(float v) {   // lane s gets lane s+1's v; s==15 -> 0
    return __int_as_float(__builtin_amdgcn_update_dpp(
        0, __float_as_int(v), 0x101, 0xF, 0xF, true));
}

// ---------------- kernel 1: per-(b,c) mean + max over H*W ----------------
__global__ __launch_bounds__(256) void pool_kernel(const float* __restrict__ x,
                                                   float* __restrict__ xavg,
                                                   float* __restrict__ xmax) {
    int plane = blockIdx.x;                       // b*C + c
    const float4* xp = (const float4*)(x + (size_t)plane * HWSZ);
    int t = threadIdx.x;
    float s = 0.f, m = -INFINITY;
    for (int i = t; i < HWSZ/4; i += 256) {       // 784 float4
        float4 v = xp[i];
        s += v.x + v.y + v.z + v.w;
        m = fmaxf(m, fmaxf(fmaxf(v.x, v.y), fmaxf(v.z, v.w)));
    }
    for (int off = 32; off; off >>= 1) {
        s += __shfl_down(s, off, 64);
        m = fmaxf(m, __shfl_down(m, off, 64));
    }
    __shared__ float ss[4], sm[4];
    int wid = t >> 6;
    if ((t & 63) == 0) { ss[wid] = s; sm[wid] = m; }
    __syncthreads();
    if (t == 0) {
        s = ss[0] + ss[1] + ss[2] + ss[3];
        m = fmaxf(fmaxf(sm[0], sm[1]), fmaxf(sm[2], sm[3]));
        xavg[plane] = s * (1.0f / HWSZ);
        xmax[plane] = m;
    }
}

// ---------------- kernel 2: GEMVs + GELU + Gx (parallel) ----------------
__global__ __launch_bounds__(256) void gemv_kernel(
        const float* __restrict__ xavg, const float* __restrict__ xmax,
        const float* __restrict__ w_avg, const float* __restrict__ b_avg,
        const float* __restrict__ w_max, const float* __restrict__ b_max,
        const float* __restrict__ w_mix,
        float* __restrict__ xw, float* __restrict__ Gx, float* __restrict__ partG) {
    int blk = blockIdx.x;
    int b  = blk / 6;
    int cg = blk - b*6;
    int t  = threadIdx.x;
    int ch = cg*64 + (t >> 2);           // output channel
    int kl = t & 3;                      // k-split lane

    const float4* wa = (const float4*)(w_avg + (size_t)ch * CC) + kl*24;
    const float4* wm = (const float4*)(w_max + (size_t)ch * CC) + kl*24;
    const float4* xa = (const float4*)(xavg + (size_t)b * CC) + kl*24;
    const float4* xm = (const float4*)(xmax + (size_t)b * CC) + kl*24;

    float acc = 0.f;
    #pragma unroll 4
    for (int q = 0; q < 24; ++q) {
        float4 a4 = wa[q], v4 = xa[q];
        acc += a4.x*v4.x + a4.y*v4.y + a4.z*v4.z + a4.w*v4.w;
    }
    #pragma unroll 4
    for (int q = 0; q < 24; ++q) {
        float4 m4 = wm[q], v4 = xm[q];
        acc += m4.x*v4.x + m4.y*v4.y + m4.z*v4.z + m4.w*v4.w;
    }
    acc += __shfl_xor(acc, 1);
    acc += __shfl_xor(acc, 2);

    float val = acc + b_avg[ch] + b_max[ch];
    float xwv = 0.5f * val * (1.0f + erff(val * 0.70710678118654752f));

    float sq = 0.f;
    const float* wr = w_mix + (size_t)ch * 49;
    #pragma unroll
    for (int i = 0; i < 13; ++i) {
        int j = kl + 4*i;
        if (j < 49) { float v = wr[j]; sq += v*v; }
    }
    sq += __shfl_xor(sq, 1);
    sq += __shfl_xor(sq, 2);
    float Gxv = fabsf(xwv) * sqrtf(sq);

    __shared__ float sg[64];
    if (kl == 0) {
        xw[b*CC + ch] = xwv;
        Gx[b*CC + ch] = Gxv;
        sg[t >> 2] = Gxv;
    }
    __syncthreads();
    if (t < 64) {
        float v = sg[t];
        for (int off = 32; off; off >>= 1) v += __shfl_down(v, off, 64);
        if (t == 0) partG[blk] = v;
    }
}

// ---------------- kernel 3: tap synthesis + direct-global depthwise 7x7 conv ----------------
// 128 threads = one plane, no LDS. Lane (s,g): 4-wide x 7-tall patch.
// One float4 load per tile row; neighbors via DPP; inner loop packed as
// float2 pairs so the backend can form v_pk_fma_f32 (2 FMA / issue).
__global__ __launch_bounds__(128) void conv_kernel(const float* __restrict__ x,
                                                   const float* __restrict__ xw,
                                                   const float* __restrict__ Gx,
                                                   const float* __restrict__ partG,
                                                   const float* __restrict__ w_mix,
                                                   const float* __restrict__ gamma,
                                                   const float* __restrict__ beta,
                                                   float* __restrict__ out) {
    int t = threadIdx.x;
    int plane = blockIdx.x;
    const float4* xp4 = (const float4*)(x + (size_t)plane * HWSZ);
    float4* op4 = (float4*)(out + (size_t)plane * HWSZ);

    // ---- tap synthesis: kfv[j] = gamma[c]*xw*Nx * w_mix[c,j] + beta[c]  (wave-uniform SGPRs)
    float kfv[49];
    {
        int b = plane / CC;
        int c = plane - b*CC;
        float sG = partG[b*6+0] + partG[b*6+1] + partG[b*6+2]
                 + partG[b*6+3] + partG[b*6+4] + partG[b*6+5];
        float xwv = xw[plane];
        float Gxv = Gx[plane];
        float gam = gamma[c];
        float bet = beta[c];
        float coef = gam * xwv * (Gxv / (sG * (1.0f/CC) + EPSF));
        const float* wr = w_mix + (size_t)c * 49;
        #pragma unroll
        for (int j = 0; j < 49; ++j) {
            union { float f; int i; } u;
            u.f = coef * wr[j] + bet;
            u.i = __builtin_amdgcn_readfirstlane(u.i);
            kfv[j] = u.f;
        }
    }

    int s = t & 15;                      // col quad (14 active)
    int g = (t >> 4) & 7;                // row-group 0..7
    bool active = (s < 14);
    int sc = active ? s : 13;
    int g7 = 7*g - 3;                    // first input row of this group's window

    float2v acc2[7][2];
    #pragma unroll
    for (int i = 0; i < 7; ++i) {
        acc2[i][0] = (float2v){0.f, 0.f};
        acc2[i][1] = (float2v){0.f, 0.f};
    }

    float4 z4 = make_float4(0.f, 0.f, 0.f, 0.f);

    // out(7g+oy, 4s+j) += k[ky][kx] * in(7g+oy+ky-3, 4s+j+kx-3)
    // w[i] = input col 4s-3+i (i=0..9): w[0..2] from left DPP, w[3..6]=vb, w[7..9] right DPP.
    // Pairs: wp[p]={w[2p],w[2p+1]}, wq[p]={w[2p+1],w[2p+2]}.
    #pragma unroll
    for (int ry = 0; ry < 13; ++ry) {
        int ri = g7 + ry;
        int ric = min(max(ri, 0), 55);
        float4 vb = xp4[ric*14 + sc];
        bool ok = ((unsigned)ri < 56u) && active;
        if (!ok) vb = z4;

        float w0 = dpp_shr1(vb.y);       // col 4s-3
        float w1 = dpp_shr1(vb.z);
        float w2 = dpp_shr1(vb.w);
        float w7 = dpp_shl1(vb.x);       // col 4s+4
        float w8 = dpp_shl1(vb.y);
        float w9 = dpp_shl1(vb.z);

        float2v wp[5], wq[4];
        wp[0] = (float2v){w0,   w1};
        wp[1] = (float2v){w2,   vb.x};
        wp[2] = (float2v){vb.y, vb.z};
        wp[3] = (float2v){vb.w, w7};
        wp[4] = (float2v){w8,   w9};
        wq[0] = (float2v){w1,   w2};
        wq[1] = (float2v){vb.x, vb.y};
        wq[2] = (float2v){vb.z, vb.w};
        wq[3] = (float2v){w7,   w8};

        int oy_lo = (ry - 6 > 0) ? (ry - 6) : 0;
        int oy_hi = (ry < 6) ? ry : 6;
        #pragma unroll
        for (int oy = 0; oy < 7; ++oy) {
            if (oy < oy_lo || oy > oy_hi) continue;
            int ky = ry - oy;
            #pragma unroll
            for (int kx = 0; kx < 7; ++kx) {
                float kv = kfv[ky*7 + kx];
                float2v kv2 = {kv, kv};
                float2v pa = (kx & 1) ? wq[kx >> 1]       : wp[kx >> 1];
                float2v pb = (kx & 1) ? wq[(kx >> 1) + 1] : wp[(kx >> 1) + 1];
                acc2[oy][0] = __builtin_elementwise_fma(kv2, pa, acc2[oy][0]);
                acc2[oy][1] = __builtin_elementwise_fma(kv2, pb, acc2[oy][1]);
            }
        }
    }

    if (active) {
        #pragma unroll
        for (int oy = 0; oy < 7; ++oy) {
            int orow = 7*g + oy;
            float4 o;
            o.x = acc2[oy][0].x; o.y = acc2[oy][0].y;
            o.z = acc2[oy][1].x; o.w = acc2[oy][1].y;
            op4[orow*14 + sc] = o;
        }
    }
}

extern "C" void kernel_launch(void* const* d_in, const int* in_sizes, int n_in,
                              void* d_out, int out_size, void* d_ws, size_t ws_size,
                              hipStream_t stream) {
    const float* x     = (const float*)d_in[0];
    const float* w_avg = (const float*)d_in[1];
    const float* b_avg = (const float*)d_in[2];
    const float* w_max = (const float*)d_in[3];
    const float* b_max = (const float*)d_in[4];
    const float* w_mix = (const float*)d_in[5];
    const float* gamma = (const float*)d_in[6];
    const float* beta  = (const float*)d_in[7];
    float* out = (float*)d_out;

    float* ws    = (float*)d_ws;
    float* xavg  = ws;                      // B*C
    float* xmax  = ws + BB*CC;              // B*C
    float* xwbuf = ws + 2*BB*CC;            // B*C
    float* Gxbuf = ws + 3*BB*CC;            // B*C
    float* partG = ws + 4*BB*CC;            // 192

    pool_kernel<<<BB*CC, 256, 0, stream>>>(x, xavg, xmax);
    gemv_kernel<<<BB*6, 256, 0, stream>>>(xavg, xmax, w_avg, b_avg, w_max, b_max,
                                          w_mix, xwbuf, Gxbuf, partG);
    conv_kernel<<<BB*CC, 128, 0, stream>>>(x, xwbuf, Gxbuf, partG, w_mix, gamma, beta, out);
}